// Round 1
// baseline (323.175 us; speedup 1.0000x reference)
//
#include <hip/hip_runtime.h>
#include <cstdint>
#include <cstddef>

// ---------------------------------------------------------------------------
// GCN+LPA on MI355X.
// R9: quarter-wave gathers. R7 falsified fetch-bound (FETCH is at the
// per-XCD compulsory floor ~127MB for fused1); R8's win axis was address/
// instruction count per edge (full-wave -> half-wave). Continue: 16 lanes
// cover a row (16B/lane for 256B rows, 8B/lane for 128B rows); one gather
// instr serves 4 edges, one 16B nt edge-load serves 2 edges/lane.
// 5 VMEM instrs / 8 edges (was 12), ~40 lane-addresses/edge (was ~96),
// bytes unchanged. Tails via quarter-uniform predication (no gather waste).
// NOTE: packing assumes N < 65536 (row/col fit 16 bits). N = 50000 here.
// ---------------------------------------------------------------------------

#define WS_ALIGN(x) (((x) + 255) & ~((size_t)255))

typedef __attribute__((ext_vector_type(8))) short short8;
typedef __attribute__((ext_vector_type(4))) float floatx4;
typedef __attribute__((ext_vector_type(4))) int intx4;

__device__ __forceinline__ unsigned short f2bf(float f) {
    unsigned u = __float_as_uint(f);
    u += 0x7fffu + ((u >> 16) & 1u);          // round-to-nearest-even
    return (unsigned short)(u >> 16);
}
__device__ __forceinline__ float bf_lo(unsigned u) { return __uint_as_float(u << 16); }
__device__ __forceinline__ float bf_hi(unsigned u) { return __uint_as_float(u & 0xffff0000u); }
__device__ __forceinline__ unsigned pack_bf2(float a, float b) {
    return (unsigned)f2bf(a) | ((unsigned)f2bf(b) << 16);
}
__device__ __forceinline__ float sigmoidf(float x) {
    return 1.f / (1.f + __expf(-x));
}
__device__ __forceinline__ int2 ld_nt_int2(const int2* p) {
    long long v = __builtin_nontemporal_load((const long long*)p);
    int2 r;
    r.x = (int)(unsigned)(v & 0xffffffffLL);
    r.y = (int)(v >> 32);
    return r;
}
// 16B edge-pair load at 8B alignment (edges[] is int2; i is arbitrary).
struct __attribute__((packed, aligned(8))) intx4_a8 { intx4 v; };
__device__ __forceinline__ intx4 ld_nt_edge2(const int2* p) {
    return __builtin_nontemporal_load(&((const intx4_a8*)p)->v);
}

static const int NBLK = 256;   // blocks for binning passes
#define MAXNB 256              // max coarse buckets supported (N <= 65536)

// ---------------------------------------------------------------------------
// CSR build: 2-level counting sort, LDS atomics only. (unchanged)
// ---------------------------------------------------------------------------
__launch_bounds__(256)
__global__ void binA_count(const int* __restrict__ row, int* __restrict__ bucket_count,
                           int* __restrict__ bases, int E, int chunk, int NB)
{
    __shared__ int hist[MAXNB];
    const int t = threadIdx.x;
    const int blk = blockIdx.x;
    if (t < NB) hist[t] = 0;
    __syncthreads();
    const int s = blk * chunk;
    const int e = min(E, s + chunk);
    for (int i = s + t; i < e; i += 256)
        atomicAdd(&hist[row[i] >> 8], 1);
    __syncthreads();
    if (t < NB)
        bases[blk * NB + t] = atomicAdd(&bucket_count[t], hist[t]);
}

__launch_bounds__(256)
__global__ void bin_scan(const int* __restrict__ bucket_count, int* __restrict__ bucket_start,
                         int NB)
{
    __shared__ int s[256];
    const int t = threadIdx.x;
    int v = (t < NB) ? bucket_count[t] : 0;
    s[t] = v;
    __syncthreads();
    for (int off = 1; off < 256; off <<= 1) {
        int u = (t >= off) ? s[t - off] : 0;
        __syncthreads();
        s[t] += u;
        __syncthreads();
    }
    int excl = s[t] - v;
    if (t <= NB) bucket_start[t] = excl;   // t==NB: total == E
}

__launch_bounds__(256)
__global__ void binA_scatter(const int* __restrict__ row, const int* __restrict__ colv,
                             const float* __restrict__ ea,
                             const int* __restrict__ bucket_start, const int* __restrict__ bases,
                             int2* __restrict__ bk, int E, int chunk, int NB)
{
    __shared__ int cur[MAXNB];
    const int t = threadIdx.x;
    const int blk = blockIdx.x;
    if (t < NB) cur[t] = bucket_start[t] + bases[blk * NB + t];
    __syncthreads();
    const int s = blk * chunk;
    const int e = min(E, s + chunk);
    for (int i = s + t; i < e; i += 256) {
        int r = row[i];
        int bin = r >> 8;
        int pos = atomicAdd(&cur[bin], 1);
        bk[pos] = make_int2(((r & 255) << 16) | colv[i], __float_as_int(ea[i]));
    }
}

__launch_bounds__(256)
__global__ void binB(const int2* __restrict__ bk, const int* __restrict__ bucket_start,
                     int* __restrict__ rowptr, int2* __restrict__ edges, int N)
{
    __shared__ int cnt[256];
    __shared__ float deg[256];
    __shared__ float inv[256];
    __shared__ int excl_s[256];
    __shared__ int cur[256];
    __shared__ int scantmp[256];
    const int b = blockIdx.x;
    const int t = threadIdx.x;
    const int s = bucket_start[b];
    const int e = bucket_start[b + 1];
    cnt[t] = 0;
    deg[t] = 0.f;
    __syncthreads();
    for (int i = s + t; i < e; i += 256) {
        int2 v = bk[i];
        int rl = ((unsigned)v.x) >> 16;
        atomicAdd(&cnt[rl], 1);
        atomicAdd(&deg[rl], __int_as_float(v.y));
    }
    __syncthreads();
    const int myc = cnt[t];
    scantmp[t] = myc;
    __syncthreads();
    for (int off = 1; off < 256; off <<= 1) {
        int u = (t >= off) ? scantmp[t - off] : 0;
        __syncthreads();
        scantmp[t] += u;
        __syncthreads();
    }
    const int excl = scantmp[t] - myc;
    excl_s[t] = excl;
    float d = deg[t];
    inv[t] = (d > 0.f) ? 1.f / d : 0.f;
    cur[t] = 0;
    const int gr = b * 256 + t;
    if (gr <= N) rowptr[gr] = s + excl;
    __syncthreads();
    for (int i = s + t; i < e; i += 256) {
        int2 v = bk[i];
        int rl = ((unsigned)v.x) >> 16;
        int c = v.x & 0xffff;
        int p = s + excl_s[rl] + atomicAdd(&cur[rl], 1);
        edges[p] = make_int2(c, __float_as_int(__int_as_float(v.y) * inv[rl]));
    }
}

// ---------------------------------------------------------------------------
// Prep (merged launch): pack W1/W2 fragments + soft f32->bf16.
// ---------------------------------------------------------------------------
template<int COLS>
__device__ __forceinline__ void pack_w_body(const float* __restrict__ W,
                                            unsigned short* __restrict__ Wp, int idx)
{
    const int total = (COLS / 16) * 4 * 64;
    if (idx >= total) return;
    const int l = idx & 63;
    const int t = (idx >> 6) & 3;
    const int ct = idx >> 8;
    const int kbase = t * 32 + (l >> 4) * 8;
    const int col = ct * 16 + (l & 15);
    unsigned short v[8];
#pragma unroll
    for (int j = 0; j < 8; ++j)
        v[j] = f2bf(W[(size_t)(kbase + j) * COLS + col]);
    uint4 o;
    o.x = (unsigned)v[0] | ((unsigned)v[1] << 16);
    o.y = (unsigned)v[2] | ((unsigned)v[3] << 16);
    o.z = (unsigned)v[4] | ((unsigned)v[5] << 16);
    o.w = (unsigned)v[6] | ((unsigned)v[7] << 16);
    *(uint4*)(Wp + (size_t)idx * 8) = o;
}

__launch_bounds__(256)
__global__ void prep_kernel(const float* __restrict__ soft, unsigned short* __restrict__ softb,
                            int ns2,
                            const float* __restrict__ w1, unsigned short* __restrict__ w1p,
                            const float* __restrict__ w2, unsigned short* __restrict__ w2p)
{
    const int b = blockIdx.x;
    const int t = threadIdx.x;
    if (b < 8) {
        pack_w_body<128>(w1, w1p, b * 256 + t);
    } else if (b < 12) {
        pack_w_body<64>(w2, w2p, (b - 8) * 256 + t);
    } else {
        int i = (b - 12) * 256 + t;
        if (i < ns2) {
            float2 v = ((const float2*)soft)[i];
            ((unsigned*)softb)[i] = pack_bf2(v.x, v.y);
        }
    }
}

// ---------------------------------------------------------------------------
// MFMA GEMM (f32 A, fused cvt): C_bf16[M,128] = bf16(A_f32[M,128]) @ Wp.
// ---------------------------------------------------------------------------
template<int COLS>
__launch_bounds__(256)
__global__ void gemm_mfma_f32a(const float* __restrict__ A,
                               const unsigned short* __restrict__ Wp,
                               unsigned short* __restrict__ C, int M)
{
    const int wave = threadIdx.x >> 6;
    const int lane = threadIdx.x & 63;
    const int row0 = blockIdx.x * 64 + wave * 16;
    const int m = lane & 15;
    const int q = lane >> 4;

    const int arow = row0 + m;
    const bool avalid = arow < M;
    short8 a[4];
#pragma unroll
    for (int t = 0; t < 4; ++t) {
        if (avalid) {
            float4 f0 = *(const float4*)(A + (size_t)arow * 128 + t * 32 + q * 8);
            float4 f1 = *(const float4*)(A + (size_t)arow * 128 + t * 32 + q * 8 + 4);
            a[t][0] = (short)f2bf(f0.x); a[t][1] = (short)f2bf(f0.y);
            a[t][2] = (short)f2bf(f0.z); a[t][3] = (short)f2bf(f0.w);
            a[t][4] = (short)f2bf(f1.x); a[t][5] = (short)f2bf(f1.y);
            a[t][6] = (short)f2bf(f1.z); a[t][7] = (short)f2bf(f1.w);
        } else {
            a[t] = (short8)0;
        }
    }

#pragma unroll
    for (int ct = 0; ct < COLS / 16; ++ct) {
        floatx4 acc = {0.f, 0.f, 0.f, 0.f};
#pragma unroll
        for (int t = 0; t < 4; ++t) {
            short8 b = *(const short8*)(Wp + (size_t)((ct * 4 + t) * 64 + lane) * 8);
            acc = __builtin_amdgcn_mfma_f32_16x16x32_bf16(a[t], b, acc, 0, 0, 0);
        }
        const int col = ct * 16 + m;
#pragma unroll
        for (int r = 0; r < 4; ++r) {
            int orow = row0 + q * 4 + r;
            if (orow < M)
                C[(size_t)orow * COLS + col] = f2bf(acc[r]);
        }
    }
}

// MFMA GEMM (bf16 A): same structure, A already bf16.
template<int COLS>
__launch_bounds__(256)
__global__ void gemm_mfma(const unsigned short* __restrict__ A,
                          const unsigned short* __restrict__ Wp,
                          unsigned short* __restrict__ C, int M)
{
    const int wave = threadIdx.x >> 6;
    const int lane = threadIdx.x & 63;
    const int row0 = blockIdx.x * 64 + wave * 16;
    const int m = lane & 15;
    const int q = lane >> 4;

    const int arow = row0 + m;
    const bool avalid = arow < M;
    short8 a[4];
#pragma unroll
    for (int t = 0; t < 4; ++t) {
        if (avalid)
            a[t] = *(const short8*)(A + (size_t)arow * 128 + t * 32 + q * 8);
        else
            a[t] = (short8)0;
    }

#pragma unroll
    for (int ct = 0; ct < COLS / 16; ++ct) {
        floatx4 acc = {0.f, 0.f, 0.f, 0.f};
#pragma unroll
        for (int t = 0; t < 4; ++t) {
            short8 b = *(const short8*)(Wp + (size_t)((ct * 4 + t) * 64 + lane) * 8);
            acc = __builtin_amdgcn_mfma_f32_16x16x32_bf16(a[t], b, acc, 0, 0, 0);
        }
        const int col = ct * 16 + m;
#pragma unroll
        for (int r = 0; r < 4; ++r) {
            int orow = row0 + q * 4 + r;
            if (orow < M)
                C[(size_t)orow * COLS + col] = f2bf(acc[r]);
        }
    }
}

// ---------------------------------------------------------------------------
// FUSED 1 (quarter-wave): F=128 stream (xw1 -> h, bias+relu)
//                       + F=64 stream (soft -> lab1).
// Wave = 1 row; 4 quarters of 16 lanes; quarter q handles edges i+2q,i+2q+1
// per iteration (8 edges/iter, 5 VMEM instrs). Lane covers 8 feats of xw1
// (uint4) and 4 feats of soft (uint2). Fold via shfl_xor(16)+shfl_xor(32).
// ---------------------------------------------------------------------------
__launch_bounds__(256)
__global__ void fused1_quad(const int* __restrict__ rowptr, const int2* __restrict__ edges,
                            const uint4* __restrict__ srcA,      // xw1 [N][16] uint4
                            const uint2* __restrict__ srcB,      // soft [N][16] uint2
                            const float* __restrict__ bias,
                            uint4* __restrict__ outA,            // h [N][16] uint4
                            uint2* __restrict__ outB,            // lab1 [N][16] uint2
                            int n)
{
    const int row = blockIdx.x * 4 + (threadIdx.x >> 6);
    const int lane = threadIdx.x & 63;
    const int f = lane & 15;
    const int q = lane >> 4;
    if (row >= n) return;
    const int s = rowptr[row];
    const int e = rowptr[row + 1];

    float A0[8], A1[8], B0[4], B1[4];
#pragma unroll
    for (int k = 0; k < 8; ++k) { A0[k] = 0.f; A1[k] = 0.f; }
#pragma unroll
    for (int k = 0; k < 4; ++k) { B0[k] = 0.f; B1[k] = 0.f; }

    int i = s;
    for (; i + 8 <= e; i += 8) {
        intx4 ed = ld_nt_edge2(&edges[i + 2 * q]);   // edges i+2q, i+2q+1
        int c0 = ed.x, c1 = ed.z;
        float wg0 = __int_as_float(ed.y);
        float wg1 = __int_as_float(ed.w);
        uint4 ua0 = srcA[c0 * 16 + f];
        uint4 ua1 = srcA[c1 * 16 + f];
        uint2 ub0 = srcB[c0 * 16 + f];
        uint2 ub1 = srcB[c1 * 16 + f];
        A0[0] = fmaf(wg0, bf_lo(ua0.x), A0[0]); A0[1] = fmaf(wg0, bf_hi(ua0.x), A0[1]);
        A0[2] = fmaf(wg0, bf_lo(ua0.y), A0[2]); A0[3] = fmaf(wg0, bf_hi(ua0.y), A0[3]);
        A0[4] = fmaf(wg0, bf_lo(ua0.z), A0[4]); A0[5] = fmaf(wg0, bf_hi(ua0.z), A0[5]);
        A0[6] = fmaf(wg0, bf_lo(ua0.w), A0[6]); A0[7] = fmaf(wg0, bf_hi(ua0.w), A0[7]);
        A1[0] = fmaf(wg1, bf_lo(ua1.x), A1[0]); A1[1] = fmaf(wg1, bf_hi(ua1.x), A1[1]);
        A1[2] = fmaf(wg1, bf_lo(ua1.y), A1[2]); A1[3] = fmaf(wg1, bf_hi(ua1.y), A1[3]);
        A1[4] = fmaf(wg1, bf_lo(ua1.z), A1[4]); A1[5] = fmaf(wg1, bf_hi(ua1.z), A1[5]);
        A1[6] = fmaf(wg1, bf_lo(ua1.w), A1[6]); A1[7] = fmaf(wg1, bf_hi(ua1.w), A1[7]);
        B0[0] = fmaf(wg0, bf_lo(ub0.x), B0[0]); B0[1] = fmaf(wg0, bf_hi(ub0.x), B0[1]);
        B0[2] = fmaf(wg0, bf_lo(ub0.y), B0[2]); B0[3] = fmaf(wg0, bf_hi(ub0.y), B0[3]);
        B1[0] = fmaf(wg1, bf_lo(ub1.x), B1[0]); B1[1] = fmaf(wg1, bf_hi(ub1.x), B1[1]);
        B1[2] = fmaf(wg1, bf_lo(ub1.y), B1[2]); B1[3] = fmaf(wg1, bf_hi(ub1.y), B1[3]);
    }
    // tail (< 8 edges): quarter q handles idx i+q and i+q+4 (quarter-uniform).
#pragma unroll
    for (int tslot = 0; tslot < 2; ++tslot) {
        int idx = i + q + tslot * 4;
        if (idx < e) {
            int2 ed = ld_nt_int2(&edges[idx]);
            float wg = __int_as_float(ed.y);
            uint4 ua = srcA[ed.x * 16 + f];
            uint2 ub = srcB[ed.x * 16 + f];
            float* A = tslot ? A1 : A0;
            float* B = tslot ? B1 : B0;
            A[0] = fmaf(wg, bf_lo(ua.x), A[0]); A[1] = fmaf(wg, bf_hi(ua.x), A[1]);
            A[2] = fmaf(wg, bf_lo(ua.y), A[2]); A[3] = fmaf(wg, bf_hi(ua.y), A[3]);
            A[4] = fmaf(wg, bf_lo(ua.z), A[4]); A[5] = fmaf(wg, bf_hi(ua.z), A[5]);
            A[6] = fmaf(wg, bf_lo(ua.w), A[6]); A[7] = fmaf(wg, bf_hi(ua.w), A[7]);
            B[0] = fmaf(wg, bf_lo(ub.x), B[0]); B[1] = fmaf(wg, bf_hi(ub.x), B[1]);
            B[2] = fmaf(wg, bf_lo(ub.y), B[2]); B[3] = fmaf(wg, bf_hi(ub.y), B[3]);
        }
    }
    // fold j-parity then quarters
#pragma unroll
    for (int k = 0; k < 8; ++k) {
        float v = A0[k] + A1[k];
        v += __shfl_xor(v, 16);
        v += __shfl_xor(v, 32);
        A0[k] = v;
    }
#pragma unroll
    for (int k = 0; k < 4; ++k) {
        float v = B0[k] + B1[k];
        v += __shfl_xor(v, 16);
        v += __shfl_xor(v, 32);
        B0[k] = v;
    }
    if (q == 0) {
        float4 bb0 = *(const float4*)(bias + 8 * f);
        float4 bb1 = *(const float4*)(bias + 8 * f + 4);
        float h0 = fmaxf(A0[0] + bb0.x, 0.f), h1 = fmaxf(A0[1] + bb0.y, 0.f);
        float h2 = fmaxf(A0[2] + bb0.z, 0.f), h3 = fmaxf(A0[3] + bb0.w, 0.f);
        float h4 = fmaxf(A0[4] + bb1.x, 0.f), h5 = fmaxf(A0[5] + bb1.y, 0.f);
        float h6 = fmaxf(A0[6] + bb1.z, 0.f), h7 = fmaxf(A0[7] + bb1.w, 0.f);
        uint4 o;
        o.x = pack_bf2(h0, h1);
        o.y = pack_bf2(h2, h3);
        o.z = pack_bf2(h4, h5);
        o.w = pack_bf2(h6, h7);
        outA[row * 16 + f] = o;
        outB[row * 16 + f] = make_uint2(pack_bf2(B0[0], B0[1]), pack_bf2(B0[2], B0[3]));
    }
}

// ---------------------------------------------------------------------------
// FUSED 2 (quarter-wave): A: logits -> out0 (bias+sigmoid, f32).
//                         B: lab1 -> lab2 (bf16 packed).
// ---------------------------------------------------------------------------
__launch_bounds__(256)
__global__ void fused2_quad(const int* __restrict__ rowptr, const int2* __restrict__ edges,
                            const uint2* __restrict__ srcA,      // logits [N][16] uint2
                            const uint2* __restrict__ srcB,      // lab1 [N][16] uint2
                            const float* __restrict__ bias,
                            float* __restrict__ outA,            // out0 f32 [N][64]
                            uint2* __restrict__ outB,            // lab2 [N][16] uint2
                            int n)
{
    const int row = blockIdx.x * 4 + (threadIdx.x >> 6);
    const int lane = threadIdx.x & 63;
    const int f = lane & 15;
    const int q = lane >> 4;
    if (row >= n) return;
    const int s = rowptr[row];
    const int e = rowptr[row + 1];

    float A0[4], A1[4], B0[4], B1[4];
#pragma unroll
    for (int k = 0; k < 4; ++k) { A0[k] = 0.f; A1[k] = 0.f; B0[k] = 0.f; B1[k] = 0.f; }

    int i = s;
    for (; i + 8 <= e; i += 8) {
        intx4 ed = ld_nt_edge2(&edges[i + 2 * q]);
        int c0 = ed.x, c1 = ed.z;
        float wg0 = __int_as_float(ed.y);
        float wg1 = __int_as_float(ed.w);
        uint2 ua0 = srcA[c0 * 16 + f];
        uint2 ua1 = srcA[c1 * 16 + f];
        uint2 ub0 = srcB[c0 * 16 + f];
        uint2 ub1 = srcB[c1 * 16 + f];
        A0[0] = fmaf(wg0, bf_lo(ua0.x), A0[0]); A0[1] = fmaf(wg0, bf_hi(ua0.x), A0[1]);
        A0[2] = fmaf(wg0, bf_lo(ua0.y), A0[2]); A0[3] = fmaf(wg0, bf_hi(ua0.y), A0[3]);
        A1[0] = fmaf(wg1, bf_lo(ua1.x), A1[0]); A1[1] = fmaf(wg1, bf_hi(ua1.x), A1[1]);
        A1[2] = fmaf(wg1, bf_lo(ua1.y), A1[2]); A1[3] = fmaf(wg1, bf_hi(ua1.y), A1[3]);
        B0[0] = fmaf(wg0, bf_lo(ub0.x), B0[0]); B0[1] = fmaf(wg0, bf_hi(ub0.x), B0[1]);
        B0[2] = fmaf(wg0, bf_lo(ub0.y), B0[2]); B0[3] = fmaf(wg0, bf_hi(ub0.y), B0[3]);
        B1[0] = fmaf(wg1, bf_lo(ub1.x), B1[0]); B1[1] = fmaf(wg1, bf_hi(ub1.x), B1[1]);
        B1[2] = fmaf(wg1, bf_lo(ub1.y), B1[2]); B1[3] = fmaf(wg1, bf_hi(ub1.y), B1[3]);
    }
#pragma unroll
    for (int tslot = 0; tslot < 2; ++tslot) {
        int idx = i + q + tslot * 4;
        if (idx < e) {
            int2 ed = ld_nt_int2(&edges[idx]);
            float wg = __int_as_float(ed.y);
            uint2 ua = srcA[ed.x * 16 + f];
            uint2 ub = srcB[ed.x * 16 + f];
            float* A = tslot ? A1 : A0;
            float* B = tslot ? B1 : B0;
            A[0] = fmaf(wg, bf_lo(ua.x), A[0]); A[1] = fmaf(wg, bf_hi(ua.x), A[1]);
            A[2] = fmaf(wg, bf_lo(ua.y), A[2]); A[3] = fmaf(wg, bf_hi(ua.y), A[3]);
            B[0] = fmaf(wg, bf_lo(ub.x), B[0]); B[1] = fmaf(wg, bf_hi(ub.x), B[1]);
            B[2] = fmaf(wg, bf_lo(ub.y), B[2]); B[3] = fmaf(wg, bf_hi(ub.y), B[3]);
        }
    }
#pragma unroll
    for (int k = 0; k < 4; ++k) {
        float v = A0[k] + A1[k];
        v += __shfl_xor(v, 16);
        v += __shfl_xor(v, 32);
        A0[k] = v;
        float u = B0[k] + B1[k];
        u += __shfl_xor(u, 16);
        u += __shfl_xor(u, 32);
        B0[k] = u;
    }
    if (q == 0) {
        float4 bb = *(const float4*)(bias + 4 * f);
        float4 o;
        o.x = sigmoidf(A0[0] + bb.x);
        o.y = sigmoidf(A0[1] + bb.y);
        o.z = sigmoidf(A0[2] + bb.z);
        o.w = sigmoidf(A0[3] + bb.w);
        *(float4*)(outA + (size_t)row * 64 + 4 * f) = o;
        outB[row * 16 + f] = make_uint2(pack_bf2(B0[0], B0[1]), pack_bf2(B0[2], B0[3]));
    }
}

// ---------------------------------------------------------------------------
// Solo SpMM F=64 (quarter-wave). ACT: 0 none (bf16 out), 3 sigmoid (f32 out).
// ---------------------------------------------------------------------------
template<int ACT>
__launch_bounds__(256)
__global__ void spmm64_quad(const int* __restrict__ rowptr, const int2* __restrict__ edges,
                            const uint2* __restrict__ src,       // [N][16] uint2
                            void* __restrict__ out, int n)
{
    const int row = blockIdx.x * 4 + (threadIdx.x >> 6);
    const int lane = threadIdx.x & 63;
    const int f = lane & 15;
    const int q = lane >> 4;
    if (row >= n) return;
    const int s = rowptr[row];
    const int e = rowptr[row + 1];

    float A0[4], A1[4];
#pragma unroll
    for (int k = 0; k < 4; ++k) { A0[k] = 0.f; A1[k] = 0.f; }

    int i = s;
    for (; i + 8 <= e; i += 8) {
        intx4 ed = ld_nt_edge2(&edges[i + 2 * q]);
        int c0 = ed.x, c1 = ed.z;
        float wg0 = __int_as_float(ed.y);
        float wg1 = __int_as_float(ed.w);
        uint2 u0 = src[c0 * 16 + f];
        uint2 u1 = src[c1 * 16 + f];
        A0[0] = fmaf(wg0, bf_lo(u0.x), A0[0]); A0[1] = fmaf(wg0, bf_hi(u0.x), A0[1]);
        A0[2] = fmaf(wg0, bf_lo(u0.y), A0[2]); A0[3] = fmaf(wg0, bf_hi(u0.y), A0[3]);
        A1[0] = fmaf(wg1, bf_lo(u1.x), A1[0]); A1[1] = fmaf(wg1, bf_hi(u1.x), A1[1]);
        A1[2] = fmaf(wg1, bf_lo(u1.y), A1[2]); A1[3] = fmaf(wg1, bf_hi(u1.y), A1[3]);
    }
#pragma unroll
    for (int tslot = 0; tslot < 2; ++tslot) {
        int idx = i + q + tslot * 4;
        if (idx < e) {
            int2 ed = ld_nt_int2(&edges[idx]);
            float wg = __int_as_float(ed.y);
            uint2 u = src[ed.x * 16 + f];
            float* A = tslot ? A1 : A0;
            A[0] = fmaf(wg, bf_lo(u.x), A[0]); A[1] = fmaf(wg, bf_hi(u.x), A[1]);
            A[2] = fmaf(wg, bf_lo(u.y), A[2]); A[3] = fmaf(wg, bf_hi(u.y), A[3]);
        }
    }
#pragma unroll
    for (int k = 0; k < 4; ++k) {
        float v = A0[k] + A1[k];
        v += __shfl_xor(v, 16);
        v += __shfl_xor(v, 32);
        A0[k] = v;
    }
    if (q == 0) {
        if (ACT == 0) {
            ((uint2*)out)[row * 16 + f] =
                make_uint2(pack_bf2(A0[0], A0[1]), pack_bf2(A0[2], A0[3]));
        } else {
            float4 o;
            o.x = sigmoidf(A0[0]);
            o.y = sigmoidf(A0[1]);
            o.z = sigmoidf(A0[2]);
            o.w = sigmoidf(A0[3]);
            *(float4*)((float*)out + (size_t)row * 64 + 4 * f) = o;
        }
    }
}

// ---------------------------------------------------------------------------
extern "C" void kernel_launch(void* const* d_in, const int* in_sizes, int n_in,
                              void* d_out, int out_size, void* d_ws, size_t ws_size,
                              hipStream_t stream)
{
    const float* x    = (const float*)d_in[0];
    const float* soft = (const float*)d_in[1];
    const float* ea   = (const float*)d_in[2];
    const float* w1   = (const float*)d_in[3];
    const float* b1   = (const float*)d_in[4];
    const float* w2   = (const float*)d_in[5];
    const float* b2   = (const float*)d_in[6];
    const int*   eidx = (const int*)d_in[7];

    const int N = in_sizes[0] / 128;
    const int E = in_sizes[2];
    const int* row  = eidx;
    const int* colv = eidx + E;
    const int NB = (N + 255) / 256;            // coarse buckets (<= 256)
    const int chunk = (E + NBLK - 1) / NBLK;

    uint8_t* ws = (uint8_t*)d_ws;
    size_t off = 0;
    auto alloc = [&](size_t bytes) -> void* {
        void* p = ws + off;
        off += WS_ALIGN(bytes);
        return p;
    };
    int*  bucket_count = (int*) alloc((size_t)NB * 4);
    int*  bucket_start = (int*) alloc(((size_t)NB + 1) * 4);
    int*  bases        = (int*) alloc((size_t)NBLK * NB * 4);
    int*  rowptr       = (int*) alloc(((size_t)N + 1) * 4);
    int2* bk           = (int2*)alloc((size_t)E * 8);
    int2* edges        = (int2*)alloc((size_t)E * 8 + 64);   // pad for vec reads
    unsigned short* w1p     = (unsigned short*)alloc((size_t)128 * 128 * 2);
    unsigned short* w2p     = (unsigned short*)alloc((size_t)128 * 64 * 2);
    unsigned short* xw1b    = (unsigned short*)alloc((size_t)N * 128 * 2);
    unsigned short* hb      = (unsigned short*)alloc((size_t)N * 128 * 2);
    unsigned short* logitsb = (unsigned short*)alloc((size_t)N * 64 * 2);
    unsigned short* softb   = (unsigned short*)alloc((size_t)N * 64 * 2);
    unsigned short* labA    = (unsigned short*)alloc((size_t)N * 64 * 2);
    unsigned short* labB    = (unsigned short*)alloc((size_t)N * 64 * 2);

    float* out0 = (float*)d_out;             // x_out [N,64]
    float* out1 = out0 + (size_t)N * 64;     // labels [N,64]

    hipMemsetAsync(bucket_count, 0, (size_t)NB * 4, stream);

    // CSR build: counting sort, LDS atomics only
    binA_count<<<NBLK, 256, 0, stream>>>(row, bucket_count, bases, E, chunk, NB);
    bin_scan<<<1, 256, 0, stream>>>(bucket_count, bucket_start, NB);
    binA_scatter<<<NBLK, 256, 0, stream>>>(row, colv, ea, bucket_start, bases, bk, E, chunk, NB);
    binB<<<NB, 256, 0, stream>>>(bk, bucket_start, rowptr, edges, N);

    // merged prep: soft -> bf16, pack W1/W2 fragments
    const int ns2 = (N * 64) / 2;
    const int gPrep = 12 + (ns2 + 255) / 256;
    prep_kernel<<<gPrep, 256, 0, stream>>>(soft, softb, ns2, w1, w1p, w2, w2p);

    const int gGemm = (N + 63) / 64;
    const int gSp   = (N + 3) / 4;

    gemm_mfma_f32a<128><<<gGemm, 256, 0, stream>>>(x, w1p, xw1b, N);     // xw1 (bf16)

    // fused pass 1: h = relu(spmm(xw1)+b1), lab1 = spmm(soft)
    fused1_quad<<<gSp, 256, 0, stream>>>(rowptr, edges, (const uint4*)xw1b,
                                         (const uint2*)softb, b1,
                                         (uint4*)hb, (uint2*)labA, N);

    gemm_mfma<64><<<gGemm, 256, 0, stream>>>(hb, w2p, logitsb, N);       // logits (bf16)

    // fused pass 2: out0 = sigmoid(spmm(logits)+b2), lab2 = spmm(lab1)
    fused2_quad<<<gSp, 256, 0, stream>>>(rowptr, edges, (const uint2*)logitsb,
                                         (const uint2*)labA, b2,
                                         out0, (uint2*)labB, N);

    // LPA tail (dependent): lab3, lab4, out1
    spmm64_quad<0><<<gSp, 256, 0, stream>>>(rowptr, edges, (const uint2*)labB, labA, N);
    spmm64_quad<0><<<gSp, 256, 0, stream>>>(rowptr, edges, (const uint2*)labA, labB, N);
    spmm64_quad<3><<<gSp, 256, 0, stream>>>(rowptr, edges, (const uint2*)labB, out1, N);
}